// Round 8
// baseline (1645.110 us; speedup 1.0000x reference)
//
#include <hip/hip_runtime.h>
#include <cstdint>
#include <cstddef>

#define T_SEQ 2048
#define DM    1024
#define HK    256
#define HV    512
#define NH    4
#define KDIM  1024
#define VDIM  2048

typedef __attribute__((ext_vector_type(8))) short bf16x8;
typedef __attribute__((ext_vector_type(8))) unsigned short u16x8;
typedef __attribute__((ext_vector_type(4))) float f32x4;
#define AS1 __attribute__((address_space(1)))
#define AS3 __attribute__((address_space(3)))

// ---------------- bf16 helpers (RNE) -----------------------------------------
static __device__ inline unsigned short f2bf(float f) {
  unsigned u = __float_as_uint(f);
  unsigned rnd = 0x7fffu + ((u >> 16) & 1u);
  return (unsigned short)((u + rnd) >> 16);
}
static __device__ inline float bf2f(unsigned short h) {
  return __uint_as_float(((unsigned)h) << 16);
}

__global__ __launch_bounds__(256) void cast_split(const float* __restrict__ in,
                                                  unsigned short* __restrict__ hi,
                                                  unsigned short* __restrict__ lo,
                                                  int n4) {
  int i = blockIdx.x * 256 + threadIdx.x;
  if (i >= n4) return;
  float4 v = ((const float4*)in)[i];
  ushort4 h, l;
  h.x = f2bf(v.x); l.x = f2bf(v.x - bf2f(h.x));
  h.y = f2bf(v.y); l.y = f2bf(v.y - bf2f(h.y));
  h.z = f2bf(v.z); l.z = f2bf(v.z - bf2f(h.z));
  h.w = f2bf(v.w); l.w = f2bf(v.w - bf2f(h.w));
  ((ushort4*)hi)[i] = h;
  ((ushort4*)lo)[i] = l;
}

// -------- split-precision bf16 MFMA GEMM: C = A @ W^T (m97 recipe) -----------
__global__ __launch_bounds__(256) void gemm_bf16s(const unsigned short* __restrict__ Ah,
                                                  const unsigned short* __restrict__ Al,
                                                  const unsigned short* __restrict__ Wh,
                                                  const unsigned short* __restrict__ Wl,
                                                  float* __restrict__ C,
                                                  int M, int N, int K) {
  __shared__ unsigned short AhS[128 * 32];
  __shared__ unsigned short AlS[128 * 32];
  __shared__ unsigned short WhS[128 * 32];
  __shared__ unsigned short WlS[128 * 32];
  const int t = threadIdx.x;
  const int l = t & 63;
  const int w = t >> 6;
  const int bm = blockIdx.y * 128;
  const int bn = blockIdx.x * 128;
  const int wm = (w >> 1) * 64;
  const int wn = (w & 1) * 64;

  f32x4 acc[4][4];
#pragma unroll
  for (int i = 0; i < 4; ++i)
#pragma unroll
    for (int j = 0; j < 4; ++j)
#pragma unroll
      for (int r = 0; r < 4; ++r) acc[i][j][r] = 0.f;

  const int srow = w * 32 + (l >> 2);
  const int scol = (l & 3) * 8;
  const size_t gOffA = (size_t)(bm + srow) * K + scol;
  const size_t gOffW = (size_t)(bn + srow) * K + scol;
  const size_t rowStep = (size_t)16 * K;
  unsigned short* lAh0 = &AhS[(w * 32) * 32];
  unsigned short* lAh1 = &AhS[(w * 32 + 16) * 32];
  unsigned short* lAl0 = &AlS[(w * 32) * 32];
  unsigned short* lAl1 = &AlS[(w * 32 + 16) * 32];
  unsigned short* lWh0 = &WhS[(w * 32) * 32];
  unsigned short* lWh1 = &WhS[(w * 32 + 16) * 32];
  unsigned short* lWl0 = &WlS[(w * 32) * 32];
  unsigned short* lWl1 = &WlS[(w * 32 + 16) * 32];

  for (int k0 = 0; k0 < K; k0 += 32) {
    __syncthreads();
    __builtin_amdgcn_global_load_lds((const AS1 void*)(Ah + gOffA + k0),           (AS3 void*)lAh0, 16, 0, 0);
    __builtin_amdgcn_global_load_lds((const AS1 void*)(Ah + gOffA + rowStep + k0), (AS3 void*)lAh1, 16, 0, 0);
    __builtin_amdgcn_global_load_lds((const AS1 void*)(Al + gOffA + k0),           (AS3 void*)lAl0, 16, 0, 0);
    __builtin_amdgcn_global_load_lds((const AS1 void*)(Al + gOffA + rowStep + k0), (AS3 void*)lAl1, 16, 0, 0);
    __builtin_amdgcn_global_load_lds((const AS1 void*)(Wh + gOffW + k0),           (AS3 void*)lWh0, 16, 0, 0);
    __builtin_amdgcn_global_load_lds((const AS1 void*)(Wh + gOffW + rowStep + k0), (AS3 void*)lWh1, 16, 0, 0);
    __builtin_amdgcn_global_load_lds((const AS1 void*)(Wl + gOffW + k0),           (AS3 void*)lWl0, 16, 0, 0);
    __builtin_amdgcn_global_load_lds((const AS1 void*)(Wl + gOffW + rowStep + k0), (AS3 void*)lWl1, 16, 0, 0);
    __syncthreads();

    bf16x8 ah[4], al[4], bh[4], bl[4];
#pragma unroll
    for (int i = 0; i < 4; ++i) {
      int aoff = (wm + i * 16 + (l & 15)) * 32 + (l >> 4) * 8;
      int boff = (wn + i * 16 + (l & 15)) * 32 + (l >> 4) * 8;
      ah[i] = *(const bf16x8*)&AhS[aoff];
      al[i] = *(const bf16x8*)&AlS[aoff];
      bh[i] = *(const bf16x8*)&WhS[boff];
      bl[i] = *(const bf16x8*)&WlS[boff];
    }
#pragma unroll
    for (int i = 0; i < 4; ++i)
#pragma unroll
      for (int j = 0; j < 4; ++j) {
        acc[i][j] = __builtin_amdgcn_mfma_f32_16x16x32_bf16(ah[i], bh[j], acc[i][j], 0, 0, 0);
        acc[i][j] = __builtin_amdgcn_mfma_f32_16x16x32_bf16(ah[i], bl[j], acc[i][j], 0, 0, 0);
        acc[i][j] = __builtin_amdgcn_mfma_f32_16x16x32_bf16(al[i], bh[j], acc[i][j], 0, 0, 0);
      }
  }

  const int cr = (l >> 4) * 4;
  const int cc = l & 15;
#pragma unroll
  for (int i = 0; i < 4; ++i)
#pragma unroll
    for (int j = 0; j < 4; ++j)
#pragma unroll
      for (int r = 0; r < 4; ++r)
        C[(size_t)(bm + wm + i * 16 + cr + r) * N + (bn + wn + j * 16 + cc)] = acc[i][j][r];
}

// ---------------- RoPE + split: q,k f32 -> qh/ql, kh/kl bf16 (q scaled) ------
__global__ __launch_bounds__(256) void rope_split(const float* __restrict__ q,
                                                  const float* __restrict__ k,
                                                  unsigned short* __restrict__ qh,
                                                  unsigned short* __restrict__ ql,
                                                  unsigned short* __restrict__ kh,
                                                  unsigned short* __restrict__ kl) {
  int idx = blockIdx.x * 256 + threadIdx.x;     // B*T*H*128
  int f  = idx & 127;
  int h  = (idx >> 7) & 3;
  int tt = (idx >> 9) & 2047;
  int b  = idx >> 20;
  size_t a0 = ((size_t)(b * T_SEQ + tt)) * KDIM + h * HK + f;
  size_t a1 = a0 + 128;
  float invf = powf(10000.0f, -(float)f * (1.0f / 128.0f));
  float ang  = (float)tt * invf;
  float s, c;
  sincosf(ang, &s, &c);
  float q1 = q[a0], q2 = q[a1];
  float q0n = (q1 * c - q2 * s) * 0.0625f;
  float q1n = (q2 * c + q1 * s) * 0.0625f;
  float k1 = k[a0], k2 = k[a1];
  float k0n = k1 * c - k2 * s;
  float k1n = k2 * c + k1 * s;
  unsigned short hh;
  hh = f2bf(q0n); qh[a0] = hh; ql[a0] = f2bf(q0n - bf2f(hh));
  hh = f2bf(q1n); qh[a1] = hh; ql[a1] = f2bf(q1n - bf2f(hh));
  hh = f2bf(k0n); kh[a0] = hh; kl[a0] = f2bf(k0n - bf2f(hh));
  hh = f2bf(k1n); kh[a1] = hh; kl[a1] = f2bf(k1n - bf2f(hh));
}

// ---------------- transpose-split v: f32 [t][dv] -> vT bf16 [bh][dv][T] ------
__global__ __launch_bounds__(256) void tsplit_v(const float* __restrict__ v,
                                                unsigned short* __restrict__ vTh,
                                                unsigned short* __restrict__ vTl) {
  const int tt = blockIdx.x, dt = blockIdx.y, bh = blockIdx.z;
  const int b = bh >> 2, h = bh & 3;
  const int t = threadIdx.x;
  __shared__ float tS[64][65];
  const int t0 = tt * 64, dv0 = dt * 64;
  const size_t vBase = ((size_t)b * T_SEQ) * VDIM + h * HV + dv0;
#pragma unroll
  for (int r = 0; r < 4; ++r) {
    int e = t + 256 * r;
    int row = e >> 4, c4 = (e & 15) * 4;
    float4 x = *(const float4*)&v[vBase + (size_t)(t0 + row) * VDIM + c4];
    tS[row][c4] = x.x; tS[row][c4 + 1] = x.y; tS[row][c4 + 2] = x.z; tS[row][c4 + 3] = x.w;
  }
  __syncthreads();
  const size_t oB = (((size_t)(b * NH + h)) * HV + dv0) * T_SEQ + t0;
#pragma unroll
  for (int r = 0; r < 2; ++r) {
    int e = t + 256 * r;
    int dvr = e >> 3, c8 = (e & 7) * 8;
    u16x8 hh, ll;
#pragma unroll
    for (int i = 0; i < 8; ++i) {
      float f = tS[c8 + i][dvr];
      unsigned short hv = f2bf(f);
      hh[i] = hv; ll[i] = f2bf(f - bf2f(hv));
    }
    *(u16x8*)&vTh[oB + (size_t)dvr * T_SEQ + c8] = hh;
    *(u16x8*)&vTl[oB + (size_t)dvr * T_SEQ + c8] = ll;
  }
}

// ------- transpose-split k WITH k_dec decay: kT_dec [bh][dk][T] --------------
// value = k[t][dk] * gamma^(63 - (t mod 64)); chunks are 64-aligned so the
// decay index is local to each 64-tile. Split happens HERE (standalone kernel,
// same idiom as cast_split) so retn_inter consumes straight copies only.
__global__ __launch_bounds__(256) void tsplit_k(const unsigned short* __restrict__ kh,
                                                const unsigned short* __restrict__ kl,
                                                unsigned short* __restrict__ kTh,
                                                unsigned short* __restrict__ kTl) {
  const int tt = blockIdx.x, dt = blockIdx.y, bh = blockIdx.z;
  const int b = bh >> 2, h = bh & 3;
  const int t = threadIdx.x;
  __shared__ float tS[64][65];
  const int t0 = tt * 64, dk0 = dt * 64;
  const float gamma = 1.0f - exp2f(-5.0f - (float)h);
  const size_t kBase = ((size_t)b * T_SEQ) * KDIM + h * HK + dk0;
#pragma unroll
  for (int r = 0; r < 2; ++r) {
    int e = t + 256 * r;
    int row = e >> 3, c8 = (e & 7) * 8;
    size_t ga = kBase + (size_t)(t0 + row) * KDIM + c8;
    u16x8 hh = *(const u16x8*)&kh[ga];
    u16x8 ll = *(const u16x8*)&kl[ga];
#pragma unroll
    for (int i = 0; i < 8; ++i)
      tS[row][c8 + i] = bf2f(hh[i]) + bf2f(ll[i]);
  }
  __syncthreads();
  const size_t oB = (((size_t)(b * NH + h)) * HK + dk0) * T_SEQ + t0;
#pragma unroll
  for (int r = 0; r < 2; ++r) {
    int e = t + 256 * r;
    int dkr = e >> 3, c8 = (e & 7) * 8;
    u16x8 hh, ll;
#pragma unroll
    for (int i = 0; i < 8; ++i) {
      float f = tS[c8 + i][dkr] * powf(gamma, (float)(63 - (c8 + i)));
      unsigned short hv = f2bf(f);
      hh[i] = hv; ll[i] = f2bf(f - bf2f(hv));
    }
    *(u16x8*)&kTh[oB + (size_t)dkr * T_SEQ + c8] = hh;
    *(u16x8*)&kTl[oB + (size_t)dkr * T_SEQ + c8] = ll;
  }
}

// ---------------- Retention pass 1: intra-chunk (f32 math, split inputs) -----
__global__ __launch_bounds__(256) void retn_intra(const unsigned short* __restrict__ qh,
                                                  const unsigned short* __restrict__ ql,
                                                  const unsigned short* __restrict__ kh,
                                                  const unsigned short* __restrict__ kl,
                                                  const unsigned short* __restrict__ vTh,
                                                  const unsigned short* __restrict__ vTl,
                                                  float* __restrict__ o) {
  const int n = blockIdx.x, h = blockIdx.y, b = blockIdx.z;
  const int t = threadIdx.x;
  const int t0 = n * 64;
  __shared__ float gpow[65];
  __shared__ float qS[64][65];
  __shared__ float kS[64][65];
  __shared__ float attnS[64][65];
  if (t <= 64) {
    float gamma = 1.0f - exp2f(-5.0f - (float)h);
    gpow[t] = powf(gamma, (float)t);
  }
  const size_t baseQK = (size_t)(b * T_SEQ + t0) * KDIM + h * HK;
  const size_t baseV  = (size_t)(b * T_SEQ + t0) * VDIM + h * HV;
  const size_t vtBase = (((size_t)(b * NH + h)) * HV) * T_SEQ;
  const int i0 = (t >> 4) * 4;
  const int j0 = (t & 15) * 4;
  float acc[4][4] = {};
  for (int s = 0; s < 4; ++s) {              // dk slices of 64
    __syncthreads();
#pragma unroll
    for (int r = 0; r < 2; ++r) {
      int e = t + 256 * r;
      int row = e >> 3, c8 = (e & 7) * 8;
      size_t ga = baseQK + (size_t)row * KDIM + s * 64 + c8;
      u16x8 hq = *(const u16x8*)&qh[ga], lq = *(const u16x8*)&ql[ga];
      u16x8 hk = *(const u16x8*)&kh[ga], lk = *(const u16x8*)&kl[ga];
#pragma unroll
      for (int i = 0; i < 8; ++i) {
        qS[row][c8 + i] = bf2f(hq[i]) + bf2f(lq[i]);
        kS[row][c8 + i] = bf2f(hk[i]) + bf2f(lk[i]);
      }
    }
    __syncthreads();
    for (int d = 0; d < 64; ++d) {
      float a0 = qS[i0][d], a1 = qS[i0 + 1][d], a2 = qS[i0 + 2][d], a3 = qS[i0 + 3][d];
#pragma unroll
      for (int jj = 0; jj < 4; ++jj) {
        float bv = kS[j0 + jj][d];
        acc[0][jj] = fmaf(a0, bv, acc[0][jj]);
        acc[1][jj] = fmaf(a1, bv, acc[1][jj]);
        acc[2][jj] = fmaf(a2, bv, acc[2][jj]);
        acc[3][jj] = fmaf(a3, bv, acc[3][jj]);
      }
    }
  }
  __syncthreads();
#pragma unroll
  for (int ii = 0; ii < 4; ++ii)
#pragma unroll
    for (int jj = 0; jj < 4; ++jj) {
      int i = i0 + ii, j = j0 + jj;
      attnS[i][j] = (i >= j) ? acc[ii][jj] * gpow[i - j] : 0.0f;
    }
  float (*vS)[65] = qS;
  for (int vb = 0; vb < 8; ++vb) {
    __syncthreads();
#pragma unroll
    for (int r = 0; r < 2; ++r) {
      int e = t + 256 * r;
      int dvr = e >> 3, c8 = (e & 7) * 8;
      size_t ga = vtBase + (size_t)(vb * 64 + dvr) * T_SEQ + t0 + c8;
      u16x8 hv = *(const u16x8*)&vTh[ga], lv = *(const u16x8*)&vTl[ga];
#pragma unroll
      for (int i = 0; i < 8; ++i)
        vS[c8 + i][dvr] = bf2f(hv[i]) + bf2f(lv[i]);
    }
    __syncthreads();
    float oa[4][4] = {};
    for (int j = 0; j < 64; ++j) {
      float a0 = attnS[i0][j], a1 = attnS[i0 + 1][j], a2 = attnS[i0 + 2][j], a3 = attnS[i0 + 3][j];
#pragma unroll
      for (int jj = 0; jj < 4; ++jj) {
        float bv = vS[j][j0 + jj];
        oa[0][jj] = fmaf(a0, bv, oa[0][jj]);
        oa[1][jj] = fmaf(a1, bv, oa[1][jj]);
        oa[2][jj] = fmaf(a2, bv, oa[2][jj]);
        oa[3][jj] = fmaf(a3, bv, oa[3][jj]);
      }
    }
#pragma unroll
    for (int ii = 0; ii < 4; ++ii)
#pragma unroll
      for (int jj = 0; jj < 4; ++jj)
        o[baseV + (size_t)(i0 + ii) * VDIM + vb * 64 + j0 + jj] = oa[ii][jj];
  }
}

// ------- Retention pass 2 (HYBRID): state update = MFMA on straight splits,
//         o_inter = verified round-6 f32 VALU loop. NO splits inside kernel.
// Grid (vt=8, h=4, b*4+dkg=16) = 512 WGs. WG: dk [dkg*64,+64), dv [vt*64,+64).
__global__ __launch_bounds__(256) void retn_inter_hybrid(
    const unsigned short* __restrict__ qh, const unsigned short* __restrict__ ql,
    const unsigned short* __restrict__ kTh, const unsigned short* __restrict__ kTl, // pre-decayed
    const unsigned short* __restrict__ vTh, const unsigned short* __restrict__ vTl,
    float* __restrict__ o) {
  const int vt  = blockIdx.x;
  const int h   = blockIdx.y;
  const int b   = blockIdx.z & 3;
  const int dkg = blockIdx.z >> 2;
  const int t = threadIdx.x;
  const int l = t & 63;
  const int w = t >> 6;
  const int quad = l >> 4;
  const int l15  = l & 15;

  __shared__ float gpow[65];
  __shared__ __align__(16) float qdS[64][68];
  __shared__ __align__(16) float sS[64][68];
  __shared__ __align__(16) unsigned short kthS[64][72], ktlS[64][72];
  __shared__ __align__(16) unsigned short vthS[64][72], vtlS[64][72];

  if (t <= 64) {
    float gamma = 1.0f - exp2f(-5.0f - (float)h);
    gpow[t] = powf(gamma, (float)t);
  }
  __syncthreads();
  const float gC = gpow[64];

  const size_t qBase  = ((size_t)b * T_SEQ) * KDIM + h * HK + dkg * 64;
  const size_t ktBase = (((size_t)(b * NH + h)) * HK + dkg * 64) * T_SEQ;
  const size_t vtBase = (((size_t)(b * NH + h)) * HV + vt * 64) * T_SEQ;
  const size_t oBase  = ((size_t)b * T_SEQ) * VDIM + h * HV + vt * 64;

  const int i0 = (t >> 4) * 4;   // o-tile rows (f32 oa loop mapping, round 6)
  const int v0 = (t & 15) * 4;   // o-tile cols

  f32x4 S[4];   // S[dk = w*16 + quad*4 + r][dv = nt*16 + l15]
#pragma unroll
  for (int nt = 0; nt < 4; ++nt)
#pragma unroll
    for (int r = 0; r < 4; ++r) S[nt][r] = 0.f;

  for (int n = 0; n < 32; ++n) {
    const int t0 = n * 64;
    __syncthreads();     // prev chunk's LDS readers done
    // ---- stage: qd (f32, reconstructed*cross_dec), kTdec + vT straight ----
#pragma unroll
    for (int r = 0; r < 2; ++r) {
      int e = t + 256 * r;
      int row = e >> 3, c8 = (e & 7) * 8;
      {
        size_t ga = qBase + (size_t)(t0 + row) * KDIM + c8;
        u16x8 hq = *(const u16x8*)&qh[ga];
        u16x8 lq = *(const u16x8*)&ql[ga];
        float gp = gpow[row + 1];
#pragma unroll
        for (int i = 0; i < 8; ++i)
          qdS[row][c8 + i] = (bf2f(hq[i]) + bf2f(lq[i])) * gp;
      }
      {
        size_t ga = ktBase + (size_t)row * T_SEQ + t0 + c8;
        *(u16x8*)&kthS[row][c8] = *(const u16x8*)&kTh[ga];
        *(u16x8*)&ktlS[row][c8] = *(const u16x8*)&kTl[ga];
      }
      {
        size_t ga = vtBase + (size_t)row * T_SEQ + t0 + c8;
        *(u16x8*)&vthS[row][c8] = *(const u16x8*)&vTh[ga];
        *(u16x8*)&vtlS[row][c8] = *(const u16x8*)&vTl[ga];
      }
    }
    // ---- publish S (f32) ----
#pragma unroll
    for (int nt = 0; nt < 4; ++nt)
#pragma unroll
      for (int r = 0; r < 4; ++r)
        sS[w * 16 + quad * 4 + r][nt * 16 + l15] = S[nt][r];
    __syncthreads();

    // ---- o_inter = qd @ S : f32 VALU (round-6 verified loop) ----
    float oa[4][4] = {};
    for (int d = 0; d < 64; d += 4) {
      float a_[4][4], s_[4][4];
#pragma unroll
      for (int ii = 0; ii < 4; ++ii)
        *(float4*)&a_[ii][0] = *(const float4*)&qdS[i0 + ii][d];
#pragma unroll
      for (int dd = 0; dd < 4; ++dd)
        *(float4*)&s_[dd][0] = *(const float4*)&sS[d + dd][v0];
#pragma unroll
      for (int dd = 0; dd < 4; ++dd)
#pragma unroll
        for (int ii = 0; ii < 4; ++ii)
#pragma unroll
          for (int jj = 0; jj < 4; ++jj)
            oa[ii][jj] = fmaf(a_[ii][dd], s_[dd][jj], oa[ii][jj]);
    }
    // ---- state update: S = gC*S + (Kdec)^T @ V  (MFMA, straight splits) ----
#pragma unroll
    for (int nt = 0; nt < 4; ++nt)
#pragma unroll
      for (int r = 0; r < 4; ++r) S[nt][r] *= gC;
#pragma unroll
    for (int ks = 0; ks < 2; ++ks) {
      bf16x8 aH = *(const bf16x8*)&kthS[w * 16 + l15][ks * 32 + quad * 8];
      bf16x8 aL = *(const bf16x8*)&ktlS[w * 16 + l15][ks * 32 + quad * 8];
#pragma unroll
      for (int nt = 0; nt < 4; ++nt) {
        bf16x8 bH = *(const bf16x8*)&vthS[nt * 16 + l15][ks * 32 + quad * 8];
        bf16x8 bL = *(const bf16x8*)&vtlS[nt * 16 + l15][ks * 32 + quad * 8];
        S[nt] = __builtin_amdgcn_mfma_f32_16x16x32_bf16(aH, bH, S[nt], 0, 0, 0);
        S[nt] = __builtin_amdgcn_mfma_f32_16x16x32_bf16(aH, bL, S[nt], 0, 0, 0);
        S[nt] = __builtin_amdgcn_mfma_f32_16x16x32_bf16(aL, bH, S[nt], 0, 0, 0);
      }
    }
    // ---- accumulate o_inter ----
#pragma unroll
    for (int ii = 0; ii < 4; ++ii) {
      size_t addr = oBase + (size_t)(t0 + i0 + ii) * VDIM + v0;
#pragma unroll
      for (int jj = 0; jj < 4; ++jj)
        atomicAdd(&o[addr + jj], oa[ii][jj]);
    }
  }
}

// ---------------- RMS group-norm over HEAD_V + SiLU(g) gate (in-place) -------
__global__ __launch_bounds__(256) void norm_gate(float* __restrict__ o,
                                                 const float* __restrict__ g,
                                                 const float* __restrict__ gnw) {
  const int row = blockIdx.x;
  const size_t base = (size_t)row * 512;
  const int t = threadIdx.x;
  float x0 = o[base + t], x1 = o[base + t + 256];
  float ss = x0 * x0 + x1 * x1;
#pragma unroll
  for (int off = 32; off > 0; off >>= 1) ss += __shfl_down(ss, off, 64);
  __shared__ float wsum[4];
  if ((t & 63) == 0) wsum[t >> 6] = ss;
  __syncthreads();
  float tot = wsum[0] + wsum[1] + wsum[2] + wsum[3];
  float scale = rsqrtf(tot * (1.0f / 512.0f) + 1e-5f);
  float g0 = g[base + t], g1 = g[base + t + 256];
  o[base + t]       = x0 * scale * gnw[t]       * (g0 / (1.0f + expf(-g0)));
  o[base + t + 256] = x1 * scale * gnw[t + 256] * (g1 / (1.0f + expf(-g1)));
}

extern "C" void kernel_launch(void* const* d_in, const int* in_sizes, int n_in,
                              void* d_out, int out_size, void* d_ws, size_t ws_size,
                              hipStream_t stream) {
  const float* x   = (const float*)d_in[0];
  const float* Wq  = (const float*)d_in[1];
  const float* Wk  = (const float*)d_in[2];
  const float* Wv  = (const float*)d_in[3];
  const float* Wg  = (const float*)d_in[4];
  const float* Wo  = (const float*)d_in[5];
  const float* gnw = (const float*)d_in[6];
  float* out = (float*)d_out;

  // workspace = 256 MiB, time-multiplexed regions:
  // A[0,32): xh/xl | B[32,64): wq/wk/wv splits -> kT splits -> wg/wo splits
  // C[64,128): f32 scratch (v, then q+k) -> o | D[128,192): vT -> g f32
  // E[192,224): qh/ql -> oh | F[224,256): kh/kl -> ol
  char* W0 = (char*)d_ws;
  unsigned short* xh  = (unsigned short*)W0;
  unsigned short* xl  = xh + 8388608;
  char* B0 = W0 + ((size_t)32 << 20);
  unsigned short* wqh = (unsigned short*)B0;
  unsigned short* wql = wqh + 1048576;
  unsigned short* wkh = wql + 1048576;
  unsigned short* wkl = wkh + 1048576;
  unsigned short* wvh = wkl + 1048576;
  unsigned short* wvl = wvh + 2097152;
  unsigned short* kTh = (unsigned short*)B0;           // overlays wq..wv (dead)
  unsigned short* kTl = kTh + 8388608;
  unsigned short* wgh = (unsigned short*)B0;           // overlays kT (dead)
  unsigned short* wgl = wgh + 2097152;
  unsigned short* woh = wgl + 2097152;
  unsigned short* wol = woh + 2097152;
  float* Cf = (float*)(W0 + ((size_t)64 << 20));       // 16M f32
  float* vf = Cf;                                      // v f32 (64 MB)
  float* qf = Cf;                                      // then q f32 (32 MB)
  float* kf = Cf + 8388608;                            // then k f32 (32 MB)
  float* o  = Cf;                                      // then o (64 MB)
  unsigned short* vTh = (unsigned short*)(W0 + ((size_t)128 << 20));
  unsigned short* vTl = vTh + 16777216;
  float* g = (float*)(W0 + ((size_t)128 << 20));       // overlays vT (dead)
  unsigned short* qh = (unsigned short*)(W0 + ((size_t)192 << 20));
  unsigned short* ql = qh + 8388608;
  unsigned short* kh = (unsigned short*)(W0 + ((size_t)224 << 20));
  unsigned short* kl = kh + 8388608;
  unsigned short* oh = (unsigned short*)(W0 + ((size_t)192 << 20));  // overlays qh/ql
  unsigned short* ol = (unsigned short*)(W0 + ((size_t)224 << 20));  // overlays kh/kl

  dim3 blk(256);
  cast_split<<<dim3(8192), blk, 0, stream>>>(x,  xh,  xl,  2097152);
  cast_split<<<dim3(1024), blk, 0, stream>>>(Wq, wqh, wql, 262144);
  cast_split<<<dim3(1024), blk, 0, stream>>>(Wk, wkh, wkl, 262144);
  cast_split<<<dim3(2048), blk, 0, stream>>>(Wv, wvh, wvl, 524288);

  gemm_bf16s<<<dim3(16, 64), blk, 0, stream>>>(xh, xl, wvh, wvl, vf, 8192, 2048, 1024);
  tsplit_v<<<dim3(32, 8, 16), blk, 0, stream>>>(vf, vTh, vTl);
  gemm_bf16s<<<dim3(8, 64),  blk, 0, stream>>>(xh, xl, wqh, wql, qf, 8192, 1024, 1024);
  gemm_bf16s<<<dim3(8, 64),  blk, 0, stream>>>(xh, xl, wkh, wkl, kf, 8192, 1024, 1024);
  rope_split<<<dim3(16384), blk, 0, stream>>>(qf, kf, qh, ql, kh, kl);
  tsplit_k<<<dim3(32, 4, 16), blk, 0, stream>>>(kh, kl, kTh, kTl);

  retn_intra<<<dim3(32, 4, 4), blk, 0, stream>>>(qh, ql, kh, kl, vTh, vTl, o);
  retn_inter_hybrid<<<dim3(8, 4, 16), blk, 0, stream>>>(qh, ql, kTh, kTl, vTh, vTl, o);

  cast_split<<<dim3(2048), blk, 0, stream>>>(Wg, wgh, wgl, 524288);
  cast_split<<<dim3(2048), blk, 0, stream>>>(Wo, woh, wol, 524288);
  gemm_bf16s<<<dim3(16, 64), blk, 0, stream>>>(xh, xl, wgh, wgl, g, 8192, 2048, 1024);
  norm_gate<<<dim3(32768), blk, 0, stream>>>(o, g, gnw);
  cast_split<<<dim3(16384), blk, 0, stream>>>(o, oh, ol, 4194304);
  gemm_bf16s<<<dim3(8, 64),  blk, 0, stream>>>(oh, ol, woh, wol, out, 8192, 1024, 2048);
}